// Round 1
// baseline (266.982 us; speedup 1.0000x reference)
//
#include <hip/hip_runtime.h>

constexpr int N_CLASSES = 1000;   // 250 float4 per label row
constexpr int EMBED     = 1024;   // 256 float4 per row; 4 float4 per lane

typedef float floatx4 __attribute__((ext_vector_type(4)));

__device__ __forceinline__ floatx4 ntload(const floatx4* p) {
    return __builtin_nontemporal_load(p);
}

// Persistent grid-stride, wave-per-row, 2-deep software pipeline with explicit
// ping-pong register sets (no rotate moves). One-hot class index is found with
// a weighted dot (labels are exactly 0.0/1.0) instead of a branchy scan, and
// the final normalization uses a single v_rsq_f32 on ff*pp. These cut per-row
// VALU from ~160 to ~95 instructions so HBM streaming is no longer VALU-gated.
__global__ __launch_bounds__(256, 4) void angular_pipelined_kernel(
    const float* __restrict__ features,
    const float* __restrict__ labels,
    const float* __restrict__ mean_class,
    float* __restrict__ partials,
    int n_rows)
{
    const int tid  = threadIdx.x;
    const int lane = tid & 63;
    const int wave = tid >> 6;
    const int wave_id = (blockIdx.x * blockDim.x + tid) >> 6;
    const int n_waves = (gridDim.x * blockDim.x) >> 6;

    // Per-lane one-hot weights: class index + 1 (bias so class 0 is nonzero).
    // Lane covers label elements {4*lane..4*lane+3} + 256*chunk.
    const float wb = (float)(4 * lane + 1);
    const floatx4 w0 = {wb,          wb + 1.f,        wb + 2.f,        wb + 3.f};
    const floatx4 w1 = {wb + 256.f,  wb + 257.f,      wb + 258.f,      wb + 259.f};
    const floatx4 w2 = {wb + 512.f,  wb + 513.f,      wb + 514.f,      wb + 515.f};
    const floatx4 w3 = {wb + 768.f,  wb + 769.f,      wb + 770.f,      wb + 771.f};

    float acc = 0.0f;

    floatx4 af0, af1, af2, af3, al0, al1, al2, al3;   // set A
    floatx4 bf0, bf1, bf2, bf3, bl0, bl1, bl2, bl3;   // set B

    #define LOAD_ROW(F0, F1, F2, F3, L0, L1, L2, L3, ROW) do {                     \
        const floatx4* frow_ = (const floatx4*)(features + (size_t)(ROW) * EMBED); \
        F0 = ntload(frow_ + lane);        F1 = ntload(frow_ + lane + 64);          \
        F2 = ntload(frow_ + lane + 128);  F3 = ntload(frow_ + lane + 192);         \
        const floatx4* lrow_ = (const floatx4*)(labels + (size_t)(ROW) * N_CLASSES); \
        L0 = ntload(lrow_ + lane);        L1 = ntload(lrow_ + lane + 64);          \
        L2 = ntload(lrow_ + lane + 128);                                           \
        L3 = (lane < N_CLASSES / 4 - 192) ? ntload(lrow_ + lane + 192)             \
                                          : (floatx4){0.f, 0.f, 0.f, 0.f};         \
    } while (0)

    #define CONSUME_ROW(F0, F1, F2, F3, L0, L1, L2, L3) do {                       \
        /* weighted one-hot dot: exact integer (class+1) in fp32 */                \
        float candf = L0.x*w0.x + L0.y*w0.y + L0.z*w0.z + L0.w*w0.w;               \
        candf += L1.x*w1.x + L1.y*w1.y + L1.z*w1.z + L1.w*w1.w;                    \
        candf += L2.x*w2.x + L2.y*w2.y + L2.z*w2.z + L2.w*w2.w;                    \
        candf += L3.x*w3.x + L3.y*w3.y + L3.z*w3.z + L3.w*w3.w;                    \
        unsigned long long m_ = __ballot(candf != 0.0f);                           \
        float clsf = __shfl(candf, __ffsll(m_) - 1, 64);                           \
        int cls = (int)clsf - 1;                                                   \
        cls = __builtin_amdgcn_readfirstlane(cls);                                 \
        const floatx4* prow_ = (const floatx4*)(mean_class + (size_t)cls * EMBED); \
        floatx4 p0 = prow_[lane];                                                  \
        floatx4 p1 = prow_[lane + 64];                                             \
        floatx4 p2 = prow_[lane + 128];                                            \
        floatx4 p3 = prow_[lane + 192];                                            \
        float ff = 0.f, pp = 0.f, fp = 0.f;                                        \
        ff += F0.x*F0.x + F0.y*F0.y + F0.z*F0.z + F0.w*F0.w;                       \
        pp += p0.x*p0.x + p0.y*p0.y + p0.z*p0.z + p0.w*p0.w;                       \
        fp += F0.x*p0.x + F0.y*p0.y + F0.z*p0.z + F0.w*p0.w;                       \
        ff += F1.x*F1.x + F1.y*F1.y + F1.z*F1.z + F1.w*F1.w;                       \
        pp += p1.x*p1.x + p1.y*p1.y + p1.z*p1.z + p1.w*p1.w;                       \
        fp += F1.x*p1.x + F1.y*p1.y + F1.z*p1.z + F1.w*p1.w;                       \
        ff += F2.x*F2.x + F2.y*F2.y + F2.z*F2.z + F2.w*F2.w;                       \
        pp += p2.x*p2.x + p2.y*p2.y + p2.z*p2.z + p2.w*p2.w;                       \
        fp += F2.x*p2.x + F2.y*p2.y + F2.z*p2.z + F2.w*p2.w;                       \
        ff += F3.x*F3.x + F3.y*F3.y + F3.z*F3.z + F3.w*F3.w;                       \
        pp += p3.x*p3.x + p3.y*p3.y + p3.z*p3.z + p3.w*p3.w;                       \
        fp += F3.x*p3.x + F3.y*p3.y + F3.z*p3.z + F3.w*p3.w;                       \
        _Pragma("unroll")                                                          \
        for (int msk_ = 1; msk_ < 64; msk_ <<= 1) {                                \
            ff += __shfl_xor(ff, msk_, 64);                                        \
            pp += __shfl_xor(pp, msk_, 64);                                        \
            fp += __shfl_xor(fp, msk_, 64);                                        \
        }                                                                          \
        acc += 1.0f - fp * __builtin_amdgcn_rsqf(fmaxf(ff * pp, 1e-24f));          \
    } while (0)

    int r = wave_id;
    if (r < n_rows) LOAD_ROW(af0, af1, af2, af3, al0, al1, al2, al3, r);

    while (r < n_rows) {
        int rn = r + n_waves;
        if (rn < n_rows) LOAD_ROW(bf0, bf1, bf2, bf3, bl0, bl1, bl2, bl3, rn);
        CONSUME_ROW(af0, af1, af2, af3, al0, al1, al2, al3);     // row r
        r = rn;
        if (r >= n_rows) break;

        rn = r + n_waves;
        if (rn < n_rows) LOAD_ROW(af0, af1, af2, af3, al0, al1, al2, al3, rn);
        CONSUME_ROW(bf0, bf1, bf2, bf3, bl0, bl1, bl2, bl3);     // row r
        r = rn;
    }

    #undef LOAD_ROW
    #undef CONSUME_ROW

    __shared__ float s_red[4];
    if (lane == 0) s_red[wave] = acc;
    __syncthreads();
    if (tid == 0)
        partials[blockIdx.x] = s_red[0] + s_red[1] + s_red[2] + s_red[3];
}

__global__ __launch_bounds__(256) void reduce_partials_kernel(
    const float* __restrict__ partials, int num_partials,
    float* __restrict__ out, float inv_n)
{
    const int tid  = threadIdx.x;
    const int lane = tid & 63;
    const int wave = tid >> 6;
    __shared__ float s_red[4];

    float acc = 0.0f;
    for (int i = tid; i < num_partials; i += 256)
        acc += partials[i];
    #pragma unroll
    for (int msk = 1; msk < 64; msk <<= 1)
        acc += __shfl_xor(acc, msk, 64);
    if (lane == 0) s_red[wave] = acc;
    __syncthreads();
    if (tid == 0)
        out[0] = (s_red[0] + s_red[1] + s_red[2] + s_red[3]) * inv_n;
}

extern "C" void kernel_launch(void* const* d_in, const int* in_sizes, int n_in,
                              void* d_out, int out_size, void* d_ws, size_t ws_size,
                              hipStream_t stream) {
    const float* features   = (const float*)d_in[0];
    const float* labels     = (const float*)d_in[1];
    const float* mean_class = (const float*)d_in[2];
    float* out = (float*)d_out;
    float* partials = (float*)d_ws;

    const int n_rows = in_sizes[0] / EMBED;   // 32768
    const int num_blocks = 1024;              // 4096 persistent waves, 8 rows each

    angular_pipelined_kernel<<<num_blocks, 256, 0, stream>>>(
        features, labels, mean_class, partials, n_rows);
    reduce_partials_kernel<<<1, 256, 0, stream>>>(
        partials, num_blocks, out, 1.0f / (float)n_rows);
}

// Round 2
// 264.001 us; speedup vs baseline: 1.0113x; 1.0113x over previous
//
#include <hip/hip_runtime.h>

constexpr int N_CLASSES = 1000;   // 250 float4 per label row
constexpr int EMBED     = 1024;   // 256 float4 per row; 4 float4 per lane

typedef float floatx4 __attribute__((ext_vector_type(4)));

__device__ __forceinline__ floatx4 ntload(const floatx4* p) {
    return __builtin_nontemporal_load(p);
}

// Persistent grid-stride, wave-per-row, 2-deep ping-pong pipeline.
// KEY ORDERING (vmcnt retires in issue order): per row we issue the 4
// prototype loads FIRST, then the 8 next-row streaming loads. The dot's wait
// for the prototypes is then vmcnt(8) -- the next-row prefetch stays in
// flight across the dot + shuffle-reduce instead of being drained by a
// vmcnt(0) every row (which was the old structure's hidden stall).
__global__ __launch_bounds__(256, 4) void angular_pipelined_kernel(
    const float* __restrict__ features,
    const float* __restrict__ labels,
    const float* __restrict__ mean_class,
    float* __restrict__ partials,
    int n_rows)
{
    const int tid  = threadIdx.x;
    const int lane = tid & 63;
    const int wave = tid >> 6;
    const int wave_id = (blockIdx.x * blockDim.x + tid) >> 6;
    const int n_waves = (gridDim.x * blockDim.x) >> 6;

    // Per-lane one-hot weights: class index + 1 (bias so class 0 is nonzero).
    const float wb = (float)(4 * lane + 1);
    const floatx4 w0 = {wb,          wb + 1.f,        wb + 2.f,        wb + 3.f};
    const floatx4 w1 = {wb + 256.f,  wb + 257.f,      wb + 258.f,      wb + 259.f};
    const floatx4 w2 = {wb + 512.f,  wb + 513.f,      wb + 514.f,      wb + 515.f};
    const floatx4 w3 = {wb + 768.f,  wb + 769.f,      wb + 770.f,      wb + 771.f};

    float acc = 0.0f;

    floatx4 af0, af1, af2, af3, al0, al1, al2, al3;   // set A
    floatx4 bf0, bf1, bf2, bf3, bl0, bl1, bl2, bl3;   // set B

    #define LOAD_ROW(F0, F1, F2, F3, L0, L1, L2, L3, ROW) do {                     \
        const floatx4* frow_ = (const floatx4*)(features + (size_t)(ROW) * EMBED); \
        F0 = ntload(frow_ + lane);        F1 = ntload(frow_ + lane + 64);          \
        F2 = ntload(frow_ + lane + 128);  F3 = ntload(frow_ + lane + 192);         \
        const floatx4* lrow_ = (const floatx4*)(labels + (size_t)(ROW) * N_CLASSES); \
        L0 = ntload(lrow_ + lane);        L1 = ntload(lrow_ + lane + 64);          \
        L2 = ntload(lrow_ + lane + 128);                                           \
        L3 = (lane < N_CLASSES / 4 - 192) ? ntload(lrow_ + lane + 192)             \
                                          : (floatx4){0.f, 0.f, 0.f, 0.f};         \
    } while (0)

    // Consume row in (F*,L*); prefetch row RN into (NF*,NL*).
    // Issue order inside: proto loads (4) -> sched_barrier -> prefetch (8).
    #define CONSUME_PREFETCH(F0, F1, F2, F3, L0, L1, L2, L3,                       \
                             NF0, NF1, NF2, NF3, NL0, NL1, NL2, NL3, RN) do {      \
        /* weighted one-hot dot: exact integer (class+1) in fp32 */                \
        float candf = L0.x*w0.x + L0.y*w0.y + L0.z*w0.z + L0.w*w0.w;               \
        candf += L1.x*w1.x + L1.y*w1.y + L1.z*w1.z + L1.w*w1.w;                    \
        candf += L2.x*w2.x + L2.y*w2.y + L2.z*w2.z + L2.w*w2.w;                    \
        candf += L3.x*w3.x + L3.y*w3.y + L3.z*w3.z + L3.w*w3.w;                    \
        unsigned long long m_ = __ballot(candf != 0.0f);                           \
        float clsf = __shfl(candf, __ffsll(m_) - 1, 64);                           \
        int cls = __builtin_amdgcn_readfirstlane((int)clsf - 1);                   \
        const floatx4* prow_ = (const floatx4*)(mean_class + (size_t)cls * EMBED); \
        floatx4 p0 = prow_[lane];                                                  \
        floatx4 p1 = prow_[lane + 64];                                             \
        floatx4 p2 = prow_[lane + 128];                                            \
        floatx4 p3 = prow_[lane + 192];                                            \
        __builtin_amdgcn_sched_barrier(0);  /* pin: proto loads issue first */     \
        if ((RN) < n_rows)                                                         \
            LOAD_ROW(NF0, NF1, NF2, NF3, NL0, NL1, NL2, NL3, RN);                  \
        float ff = 0.f, pp = 0.f, fp = 0.f;                                        \
        ff += F0.x*F0.x + F0.y*F0.y + F0.z*F0.z + F0.w*F0.w;                       \
        pp += p0.x*p0.x + p0.y*p0.y + p0.z*p0.z + p0.w*p0.w;                       \
        fp += F0.x*p0.x + F0.y*p0.y + F0.z*p0.z + F0.w*p0.w;                       \
        ff += F1.x*F1.x + F1.y*F1.y + F1.z*F1.z + F1.w*F1.w;                       \
        pp += p1.x*p1.x + p1.y*p1.y + p1.z*p1.z + p1.w*p1.w;                       \
        fp += F1.x*p1.x + F1.y*p1.y + F1.z*p1.z + F1.w*p1.w;                       \
        ff += F2.x*F2.x + F2.y*F2.y + F2.z*F2.z + F2.w*F2.w;                       \
        pp += p2.x*p2.x + p2.y*p2.y + p2.z*p2.z + p2.w*p2.w;                       \
        fp += F2.x*p2.x + F2.y*p2.y + F2.z*p2.z + F2.w*p2.w;                       \
        ff += F3.x*F3.x + F3.y*F3.y + F3.z*F3.z + F3.w*F3.w;                       \
        pp += p3.x*p3.x + p3.y*p3.y + p3.z*p3.z + p3.w*p3.w;                       \
        fp += F3.x*p3.x + F3.y*p3.y + F3.z*p3.z + F3.w*p3.w;                       \
        _Pragma("unroll")                                                          \
        for (int msk_ = 1; msk_ < 64; msk_ <<= 1) {                                \
            ff += __shfl_xor(ff, msk_, 64);                                        \
            pp += __shfl_xor(pp, msk_, 64);                                        \
            fp += __shfl_xor(fp, msk_, 64);                                        \
        }                                                                          \
        acc += 1.0f - fp * __builtin_amdgcn_rsqf(fmaxf(ff * pp, 1e-24f));          \
    } while (0)

    int r = wave_id;
    if (r < n_rows) LOAD_ROW(af0, af1, af2, af3, al0, al1, al2, al3, r);

    while (r < n_rows) {
        int rn = r + n_waves;
        CONSUME_PREFETCH(af0, af1, af2, af3, al0, al1, al2, al3,
                         bf0, bf1, bf2, bf3, bl0, bl1, bl2, bl3, rn);
        r = rn;
        if (r >= n_rows) break;

        rn = r + n_waves;
        CONSUME_PREFETCH(bf0, bf1, bf2, bf3, bl0, bl1, bl2, bl3,
                         af0, af1, af2, af3, al0, al1, al2, al3, rn);
        r = rn;
    }

    #undef LOAD_ROW
    #undef CONSUME_PREFETCH

    __shared__ float s_red[4];
    if (lane == 0) s_red[wave] = acc;
    __syncthreads();
    if (tid == 0)
        partials[blockIdx.x] = s_red[0] + s_red[1] + s_red[2] + s_red[3];
}

__global__ __launch_bounds__(256) void reduce_partials_kernel(
    const float* __restrict__ partials, int num_partials,
    float* __restrict__ out, float inv_n)
{
    const int tid  = threadIdx.x;
    const int lane = tid & 63;
    const int wave = tid >> 6;
    __shared__ float s_red[4];

    float acc = 0.0f;
    for (int i = tid; i < num_partials; i += 256)
        acc += partials[i];
    #pragma unroll
    for (int msk = 1; msk < 64; msk <<= 1)
        acc += __shfl_xor(acc, msk, 64);
    if (lane == 0) s_red[wave] = acc;
    __syncthreads();
    if (tid == 0)
        out[0] = (s_red[0] + s_red[1] + s_red[2] + s_red[3]) * inv_n;
}

extern "C" void kernel_launch(void* const* d_in, const int* in_sizes, int n_in,
                              void* d_out, int out_size, void* d_ws, size_t ws_size,
                              hipStream_t stream) {
    const float* features   = (const float*)d_in[0];
    const float* labels     = (const float*)d_in[1];
    const float* mean_class = (const float*)d_in[2];
    float* out = (float*)d_out;
    float* partials = (float*)d_ws;

    const int n_rows = in_sizes[0] / EMBED;   // 32768
    const int num_blocks = 1024;              // 4096 persistent waves, 8 rows each

    angular_pipelined_kernel<<<num_blocks, 256, 0, stream>>>(
        features, labels, mean_class, partials, n_rows);
    reduce_partials_kernel<<<1, 256, 0, stream>>>(
        partials, num_blocks, out, 1.0f / (float)n_rows);
}